// Round 1
// baseline (99.433 us; speedup 1.0000x reference)
//
#include <hip/hip_runtime.h>
#include <stdint.h>

// LUTLayer forward, MI355X (gfx950).
// x: (2048, 4096) f32 in {0,1}; mapping: (4096, 6) i32; luts: (4096, 64) f32.
// out[b][j] = (luts[j][ sum_k x[b][mapping[j][k]] << k ] > 0) ? 1.0f : 0.0f
//
// R2: single fused kernel, zero workspace use.
//  - 256 blocks x 512 threads; block = (row-group g [32 rows], col-block cb [1024 cols]).
//  - Phase A: pack own 32x4096 x-slice into 16 KB LDS bit-image (transposed bit-pack:
//    bit r of sbits[m] = x[g*32+r][m] != 0). x re-read factor is 4 (4 col-blocks per g),
//    recovered by same-XCD co-location: xcd = bid%8; the 4 blocks of one g are adjacent
//    slots on one XCD, so the slice is fetched to that XCD's L2 once (per-XCD unique
//    footprint 8 slices = 4 MB = L2 size; 256 MB L3 backstops).
//  - Phase B: 64-bit lut sign masks via wave ballot into 8 KB LDS (clip[-1,1] preserves
//    sign, so only sign matters).
//  - Phase C: 12 LDS word-gathers per thread -> 32 rows x 2 cols pure VALU, nontemporal
//    float2 stores (don't let the 33.5 MB out stream evict the shared x lines in L2).
// Removes: xbits global round-trip (1 MB write + 8 MB read), lut_pos round-trip,
// one kernel launch + gap, and the serialization of x-read vs out-write phases.

static constexpr int IN    = 4096;
static constexpr int OUTW  = 4096;
static constexpr int BATCH = 2048;

typedef float vfloat2 __attribute__((ext_vector_type(2)));

__global__ __launch_bounds__(512) void fused_kernel(const float* __restrict__ x,
                                                    const int* __restrict__ mapping,
                                                    const float* __restrict__ luts,
                                                    float* __restrict__ out) {
    __shared__ uint32_t sbits[IN];                  // 16 KB bit image for this row-group
    __shared__ unsigned long long smask[1024];      // 8 KB lut sign masks for this col-block

    // XCD-aware decode: xcd = bid & 7; within an XCD, 4 consecutive slots share one g.
    const int bid  = blockIdx.x;
    const int slot = bid >> 3;                      // 0..31 within this XCD
    const int g    = (bid & 7) * 8 + (slot >> 2);   // row-group 0..63
    const int cb   = slot & 3;                      // col-block 0..3 (1024 cols)

    // ---- Phase A: pack x bits for row-group g (all 4096 input cols) ----
#pragma unroll
    for (int c = 0; c < 2; ++c) {
        const int m = c * 2048 + threadIdx.x * 4;   // this thread's 4 cols
        const float* xb = x + ((size_t)g * 32) * IN + m;
        uint32_t v0 = 0, v1 = 0, v2 = 0, v3 = 0;
#pragma unroll
        for (int r = 0; r < 32; ++r) {
            const float4 f = *(const float4*)(xb + (size_t)r * IN);
            v0 |= ((uint32_t)(f.x != 0.0f)) << r;
            v1 |= ((uint32_t)(f.y != 0.0f)) << r;
            v2 |= ((uint32_t)(f.z != 0.0f)) << r;
            v3 |= ((uint32_t)(f.w != 0.0f)) << r;
        }
        *(uint4*)(sbits + m) = make_uint4(v0, v1, v2, v3);
    }

    // ---- Phase B: lut sign masks for this col-block (wave-cooperative ballot) ----
    {
        const int wave  = threadIdx.x >> 6;         // 0..7
        const int lane  = threadIdx.x & 63;
        const int cbase = wave * 128;               // col within block
        const float* lp = luts + ((size_t)(cb * 1024 + cbase)) * 64 + lane;
#pragma unroll
        for (int i = 0; i < 128; i += 4) {
            const float v0 = lp[(size_t)(i + 0) * 64];
            const float v1 = lp[(size_t)(i + 1) * 64];
            const float v2 = lp[(size_t)(i + 2) * 64];
            const float v3 = lp[(size_t)(i + 3) * 64];
            const unsigned long long m0 = __ballot(v0 > 0.0f);
            const unsigned long long m1 = __ballot(v1 > 0.0f);
            const unsigned long long m2 = __ballot(v2 > 0.0f);
            const unsigned long long m3 = __ballot(v3 > 0.0f);
            if (lane == 0) {
                smask[cbase + i + 0] = m0;
                smask[cbase + i + 1] = m1;
                smask[cbase + i + 2] = m2;
                smask[cbase + i + 3] = m3;
            }
        }
    }
    __syncthreads();

    // ---- Phase C: compute 32 rows x 2 cols per thread ----
    const int jl = threadIdx.x * 2;                 // col within block
    const int j  = cb * 1024 + jl;                  // global output col
    const int4* mrow = (const int4*)(mapping + (size_t)j * 6);  // 12 ints, 16B-aligned
    const int4 q0 = mrow[0];   // c0: k0..k3
    const int4 q1 = mrow[1];   // c0: k4,k5 ; c1: k0,k1
    const int4 q2 = mrow[2];   // c1: k2..k5

    const uint32_t w00 = sbits[q0.x], w01 = sbits[q0.y], w02 = sbits[q0.z],
                   w03 = sbits[q0.w], w04 = sbits[q1.x], w05 = sbits[q1.y];
    const uint32_t w10 = sbits[q1.z], w11 = sbits[q1.w], w12 = sbits[q2.x],
                   w13 = sbits[q2.y], w14 = sbits[q2.z], w15 = sbits[q2.w];
    const unsigned long long mk0 = smask[jl];
    const unsigned long long mk1 = smask[jl + 1];

    float* outp = out + ((size_t)g * 32) * OUTW + j;
#pragma unroll
    for (int r = 0; r < 32; ++r) {
        const uint32_t a0 = ((w00 >> r) & 1u)        | (((w01 >> r) & 1u) << 1)
                          | (((w02 >> r) & 1u) << 2) | (((w03 >> r) & 1u) << 3)
                          | (((w04 >> r) & 1u) << 4) | (((w05 >> r) & 1u) << 5);
        const uint32_t a1 = ((w10 >> r) & 1u)        | (((w11 >> r) & 1u) << 1)
                          | (((w12 >> r) & 1u) << 2) | (((w13 >> r) & 1u) << 3)
                          | (((w14 >> r) & 1u) << 4) | (((w15 >> r) & 1u) << 5);
        vfloat2 res;
        res.x = (float)((uint32_t)(mk0 >> a0) & 1u);
        res.y = (float)((uint32_t)(mk1 >> a1) & 1u);
        __builtin_nontemporal_store(res, (vfloat2*)(outp + (size_t)r * OUTW));
    }
}

extern "C" void kernel_launch(void* const* d_in, const int* in_sizes, int n_in,
                              void* d_out, int out_size, void* d_ws, size_t ws_size,
                              hipStream_t stream) {
    const float* x       = (const float*)d_in[0];
    const int*   mapping = (const int*)d_in[1];
    const float* luts    = (const float*)d_in[2];
    float* out = (float*)d_out;
    (void)d_ws; (void)ws_size;

    hipLaunchKernelGGL(fused_kernel, dim3(256), dim3(512), 0, stream,
                       x, mapping, luts, out);
}

// Round 3
// 98.472 us; speedup vs baseline: 1.0098x; 1.0098x over previous
//
#include <hip/hip_runtime.h>
#include <stdint.h>

// LUTLayer forward, MI355X (gfx950).
// x: (2048, 4096) f32 in {0,1}; mapping: (4096, 6) i32; luts: (4096, 64) f32.
// out[b][j] = (luts[j][ sum_k x[b][mapping[j][k]] << k ] > 0) ? 1.0f : 0.0f
//
// R4 == R3 resubmit (R3 bench was an infra failure, no counters).
// Read-once main kernel: block = (4 rows x ALL 4096 cols), so x is read exactly
// once by construction (R2's (g,cb) split re-read x 4x; L2-dedup bet failed).
//  - lutprep (16 blocks): lut_pos[j] = 64-bit ballot of (luts[j][e] > 0).
//    1 MB read / 32 KB write, ~1-2 us.
//  - main (512 blocks x 256 threads, 2 blocks/CU):
//    Phase A: pack own 4x4096 slice into 16 KB LDS nibble image (bit r of
//      sbits[m] = x[g*4+r][m] != 0), nontemporal float4 loads.
//    Phase B: per thread 4 chunks x 4 cols: 6 int4 mapping loads, 24 LDS
//      gathers, 2 ulonglong2 mask loads, then 4 rows x 4 cols pure VALU and
//      nontemporal float4 stores.
// Traffic: 33.5 MB x read + 33.5 MB out write + ~1.1 MB tables (L2-resident).

static constexpr int IN    = 4096;
static constexpr int OUTW  = 4096;
static constexpr int BATCH = 2048;

typedef float vfloat4 __attribute__((ext_vector_type(4)));

__global__ __launch_bounds__(256) void lutprep_kernel(const float* __restrict__ luts,
                                                      unsigned long long* __restrict__ lut_pos) {
    // 16 blocks x 4 waves x 64 luts, 4-wide pipelined ballots.
    const int wave = threadIdx.x >> 6;
    const int lane = threadIdx.x & 63;
    const int base = blockIdx.x * 256 + wave * 64;
#pragma unroll
    for (int i = 0; i < 64; i += 4) {
        const float v0 = luts[(size_t)(base + i + 0) * 64 + lane];
        const float v1 = luts[(size_t)(base + i + 1) * 64 + lane];
        const float v2 = luts[(size_t)(base + i + 2) * 64 + lane];
        const float v3 = luts[(size_t)(base + i + 3) * 64 + lane];
        const unsigned long long m0 = __ballot(v0 > 0.0f);
        const unsigned long long m1 = __ballot(v1 > 0.0f);
        const unsigned long long m2 = __ballot(v2 > 0.0f);
        const unsigned long long m3 = __ballot(v3 > 0.0f);
        if (lane == 0) {
            lut_pos[base + i + 0] = m0;
            lut_pos[base + i + 1] = m1;
            lut_pos[base + i + 2] = m2;
            lut_pos[base + i + 3] = m3;
        }
    }
}

__global__ __launch_bounds__(256) void lut_main_kernel(const float* __restrict__ x,
                                                       const int* __restrict__ mapping,
                                                       const unsigned long long* __restrict__ lut_pos,
                                                       float* __restrict__ out) {
    __shared__ uint32_t sbits[IN];          // 16 KB nibble image (low 4 bits used)
    const int g = blockIdx.x;               // 4-row group, 0..511
    const int t = threadIdx.x;

    // ---- Phase A: pack 4 rows x 4096 cols, x read exactly once ----
#pragma unroll
    for (int c = 0; c < 4; ++c) {
        const int m = c * 1024 + t * 4;
        const float* xb = x + ((size_t)g * 4) * IN + m;
        uint32_t v0 = 0, v1 = 0, v2 = 0, v3 = 0;
#pragma unroll
        for (int r = 0; r < 4; ++r) {
            const vfloat4 f = __builtin_nontemporal_load((const vfloat4*)(xb + (size_t)r * IN));
            v0 |= ((uint32_t)(f.x != 0.0f)) << r;
            v1 |= ((uint32_t)(f.y != 0.0f)) << r;
            v2 |= ((uint32_t)(f.z != 0.0f)) << r;
            v3 |= ((uint32_t)(f.w != 0.0f)) << r;
        }
        *(uint4*)(sbits + m) = make_uint4(v0, v1, v2, v3);
    }
    __syncthreads();

    // ---- Phase B: 4 chunks x 4 cols x 4 rows per thread ----
#pragma unroll
    for (int c = 0; c < 4; ++c) {
        const int j = c * 1024 + t * 4;                           // cols j..j+3
        const int4* mrow = (const int4*)(mapping + (size_t)j * 6); // 24 ints, 16B-aligned
        const int4 q0 = mrow[0];  // c0: k0..k3
        const int4 q1 = mrow[1];  // c0: k4,k5 ; c1: k0,k1
        const int4 q2 = mrow[2];  // c1: k2..k5
        const int4 q3 = mrow[3];  // c2: k0..k3
        const int4 q4 = mrow[4];  // c2: k4,k5 ; c3: k0,k1
        const int4 q5 = mrow[5];  // c3: k2..k5

        const uint32_t w00 = sbits[q0.x], w01 = sbits[q0.y], w02 = sbits[q0.z],
                       w03 = sbits[q0.w], w04 = sbits[q1.x], w05 = sbits[q1.y];
        const uint32_t w10 = sbits[q1.z], w11 = sbits[q1.w], w12 = sbits[q2.x],
                       w13 = sbits[q2.y], w14 = sbits[q2.z], w15 = sbits[q2.w];
        const uint32_t w20 = sbits[q3.x], w21 = sbits[q3.y], w22 = sbits[q3.z],
                       w23 = sbits[q3.w], w24 = sbits[q4.x], w25 = sbits[q4.y];
        const uint32_t w30 = sbits[q4.z], w31 = sbits[q4.w], w32 = sbits[q5.x],
                       w33 = sbits[q5.y], w34 = sbits[q5.z], w35 = sbits[q5.w];

        const ulonglong2 mk01 = *(const ulonglong2*)(lut_pos + j);
        const ulonglong2 mk23 = *(const ulonglong2*)(lut_pos + j + 2);

        float* outp = out + ((size_t)g * 4) * OUTW + j;
#pragma unroll
        for (int r = 0; r < 4; ++r) {
            const uint32_t a0 = ((w00 >> r) & 1u)        | (((w01 >> r) & 1u) << 1)
                              | (((w02 >> r) & 1u) << 2) | (((w03 >> r) & 1u) << 3)
                              | (((w04 >> r) & 1u) << 4) | (((w05 >> r) & 1u) << 5);
            const uint32_t a1 = ((w10 >> r) & 1u)        | (((w11 >> r) & 1u) << 1)
                              | (((w12 >> r) & 1u) << 2) | (((w13 >> r) & 1u) << 3)
                              | (((w14 >> r) & 1u) << 4) | (((w15 >> r) & 1u) << 5);
            const uint32_t a2 = ((w20 >> r) & 1u)        | (((w21 >> r) & 1u) << 1)
                              | (((w22 >> r) & 1u) << 2) | (((w23 >> r) & 1u) << 3)
                              | (((w24 >> r) & 1u) << 4) | (((w25 >> r) & 1u) << 5);
            const uint32_t a3 = ((w30 >> r) & 1u)        | (((w31 >> r) & 1u) << 1)
                              | (((w32 >> r) & 1u) << 2) | (((w33 >> r) & 1u) << 3)
                              | (((w34 >> r) & 1u) << 4) | (((w35 >> r) & 1u) << 5);
            vfloat4 res;
            res.x = (float)((uint32_t)(mk01.x >> a0) & 1u);
            res.y = (float)((uint32_t)(mk01.y >> a1) & 1u);
            res.z = (float)((uint32_t)(mk23.x >> a2) & 1u);
            res.w = (float)((uint32_t)(mk23.y >> a3) & 1u);
            __builtin_nontemporal_store(res, (vfloat4*)(outp + (size_t)r * OUTW));
        }
    }
}

// Fallback if workspace is too small for lut_pos: direct per-output computation.
__global__ __launch_bounds__(256) void naive_kernel(const float* __restrict__ x,
                                                    const int* __restrict__ mapping,
                                                    const float* __restrict__ luts,
                                                    float* __restrict__ out) {
    const int idx = blockIdx.x * 256 + threadIdx.x;
    if (idx >= BATCH * OUTW) return;
    const int b = idx >> 12;
    const int j = idx & (OUTW - 1);
    const float* xr = x + (size_t)b * IN;
    int addr = 0;
#pragma unroll
    for (int k = 0; k < 6; ++k) {
        addr |= ((int)(xr[mapping[j * 6 + k]] != 0.0f)) << k;
    }
    out[idx] = (luts[j * 64 + addr] > 0.0f) ? 1.0f : 0.0f;
}

extern "C" void kernel_launch(void* const* d_in, const int* in_sizes, int n_in,
                              void* d_out, int out_size, void* d_ws, size_t ws_size,
                              hipStream_t stream) {
    const float* x       = (const float*)d_in[0];
    const int*   mapping = (const int*)d_in[1];
    const float* luts    = (const float*)d_in[2];
    float* out = (float*)d_out;

    const size_t lut_pos_bytes = (size_t)OUTW * 8;   // 32 KB
    if (ws_size >= lut_pos_bytes) {
        unsigned long long* lut_pos = (unsigned long long*)d_ws;
        hipLaunchKernelGGL(lutprep_kernel, dim3(16), dim3(256), 0, stream,
                           luts, lut_pos);
        hipLaunchKernelGGL(lut_main_kernel, dim3(512), dim3(256), 0, stream,
                           x, mapping, lut_pos, out);
    } else {
        hipLaunchKernelGGL(naive_kernel, dim3((BATCH * OUTW) / 256), dim3(256), 0, stream,
                           x, mapping, luts, out);
    }
}